// Round 12
// baseline (540.029 us; speedup 1.0000x reference)
//
#include <hip/hip_runtime.h>

typedef __attribute__((ext_vector_type(8))) __bf16 bf16x8;
typedef __attribute__((ext_vector_type(4))) float f32x4;

#define NEG_BIG (-1e30f)

__device__ __forceinline__ unsigned short f2b(float f) {
    unsigned int u = __float_as_uint(f);
    u += 0x7FFFu + ((u >> 16) & 1u);
    return (unsigned short)(u >> 16);
}
__device__ __forceinline__ float b2f(unsigned short h) {
    return __uint_as_float(((unsigned int)h) << 16);
}
__device__ __forceinline__ unsigned cvtpk(float lo, float hi) {
    unsigned r;
    asm("v_cvt_pk_bf16_f32 %0, %1, %2" : "=v"(r) : "v"(lo), "v"(hi));
    return r;
}

typedef const __attribute__((address_space(1))) unsigned int* gas_ptr;
typedef __attribute__((address_space(3))) unsigned int* las_ptr;
__device__ __forceinline__ void gload16(const void* g, void* l) {
    __builtin_amdgcn_global_load_lds((gas_ptr)g, (las_ptr)l, 16, 0, 0);
}

// ---------------- elementwise f32 -> bf16 (rn) ----------------
__global__ __launch_bounds__(256) void k_convert(
    const float* __restrict__ x, unsigned short* __restrict__ xb, int n4)
{
    int i = blockIdx.x * 256 + threadIdx.x;
    if (i >= n4) return;
    float4 v = reinterpret_cast<const float4*>(x)[i];
    ushort4 h;
    h.x = f2b(v.x); h.y = f2b(v.y); h.z = f2b(v.z); h.w = f2b(v.w);
    reinterpret_cast<ushort4*>(xb)[i] = h;
}

// ------------- W (K x N, f32) -> Wt (N x K) bf16 -------------
__global__ __launch_bounds__(256) void k_transpose(
    const float* __restrict__ W, unsigned short* __restrict__ Th, int K, int N)
{
    __shared__ float tile[64][65];
    const int n0 = blockIdx.x * 64, k0 = blockIdx.y * 64;
    const int c = threadIdx.x & 63, r0 = threadIdx.x >> 6;
    for (int rr = r0; rr < 64; rr += 4)
        tile[rr][c] = W[(size_t)(k0 + rr) * N + n0 + c];
    __syncthreads();
    for (int rr = r0; rr < 64; rr += 4)
        Th[(size_t)(n0 + rr) * K + k0 + c] = f2b(tile[c][rr]);
}

// ------------- plain bf16 GEMM: C = A * B^T(stored [N][K]) -------------
// Split epilogue: cols < N1 -> CoutA (row stride NA), cols >= N1 -> CoutB
// (row stride NB, col - N1). 128x128 tile, BK=32, 4 waves.
__global__ __launch_bounds__(256) void k_gemm(
    const unsigned short* __restrict__ A, const unsigned short* __restrict__ B,
    void* __restrict__ CoutA, int NA, void* __restrict__ CoutB, int NB, int N1,
    const float* __restrict__ bias, int M, int K, int outF32)
{
    __shared__ __align__(16) unsigned short As[128][32];
    __shared__ __align__(16) unsigned short Bs[128][32];

    const int tid  = threadIdx.x;
    const int lane = tid & 63, wid = tid >> 6;
    const int wr = wid >> 1, wc = wid & 1;
    const int lrow = lane & 15, lko = (lane >> 4) << 3;
    const int trow = tid >> 2, tk = (tid & 3) << 3;
    const int bm = blockIdx.y, bn = blockIdx.x;
    const int wbyte = wid * 1024;   // lane-linear: thread t -> byte 16*t

    f32x4 acc[4][4] = {};

    const size_t aoff = (size_t)(bm * 128 + trow) * K + tk;
    const size_t boff = (size_t)(bn * 128 + trow) * K + tk;
    const size_t half = (size_t)64 * K;

    for (int k0 = 0; k0 < K; k0 += 32) {
        gload16(&A[aoff + k0],        (char*)&As[0][0] + wbyte);
        gload16(&A[aoff + half + k0], (char*)&As[0][0] + 4096 + wbyte);
        gload16(&B[boff + k0],        (char*)&Bs[0][0] + wbyte);
        gload16(&B[boff + half + k0], (char*)&Bs[0][0] + 4096 + wbyte);
        __syncthreads();

        bf16x8 af[4], bf[4];
        #pragma unroll
        for (int m = 0; m < 4; ++m)
            af[m] = *reinterpret_cast<const bf16x8*>(&As[wr * 64 + m * 16 + lrow][lko]);
        #pragma unroll
        for (int n = 0; n < 4; ++n)
            bf[n] = *reinterpret_cast<const bf16x8*>(&Bs[wc * 64 + n * 16 + lrow][lko]);
        #pragma unroll
        for (int m = 0; m < 4; ++m)
            #pragma unroll
            for (int n = 0; n < 4; ++n)
                acc[m][n] = __builtin_amdgcn_mfma_f32_16x16x32_bf16(af[m], bf[n], acc[m][n], 0, 0, 0);
        __syncthreads();
    }

    const int rbase = bm * 128 + wr * 64 + ((lane >> 4) << 2);
    const int cbase = bn * 128 + wc * 64 + lrow;
    #pragma unroll
    for (int m = 0; m < 4; ++m)
        #pragma unroll
        for (int n = 0; n < 4; ++n) {
            const int col = cbase + n * 16;
            const float bv = bias ? bias[col] : 0.0f;
            const bool inA = (col < N1);
            const int ccol = inA ? col : (col - N1);
            const int cstr = inA ? NA : NB;
            void* base = inA ? CoutA : CoutB;
            #pragma unroll
            for (int r = 0; r < 4; ++r) {
                const size_t idx = (size_t)(rbase + m * 16 + r) * cstr + ccol;
                const float v = acc[m][n][r] + bv;
                if (outF32) ((float*)base)[idx] = v;
                else        ((unsigned short*)base)[idx] = f2b(v);
            }
        }
}

// ------------- fused causal GQA attention with ALiBi -------------
// block = (b, g, 32-row q-chunk), 8 waves (512 thr): waves 0-3 = q-tile q0,
// waves 4-7 = q-tile q0+16 (same kv head g). Shared K/V staging. Verified
// r5/r9 skeleton. This round: exp2-domain softmax, wave-uniform unmasked
// fast path, defer-max (T13, log2 THR=12).
__global__ __launch_bounds__(512, 4) void k_attn(
    const unsigned short* __restrict__ Qb,   // (B*T) x 2048 bf16
    const unsigned short* __restrict__ KVb,  // (B*T) x 1024 bf16 (k | v)
    unsigned short* __restrict__ AO)         // (B*T) x 2048 bf16
{
    __shared__ __align__(16) unsigned short Ksl[64][128]; // [key][dim ^ ((key&7)<<3)]
    __shared__ __align__(16) unsigned short Vt[128][72];  // [dim][key], padded
    __shared__ __align__(16) unsigned short Psl[8][16][72];

    const int blk = blockIdx.x;
    const int idx = blk >> 3;          // 0..63
    const int sub = blk & 7;
    const int b   = sub >> 2;
    const int g   = sub & 3;
    const int chunk = (idx < 32) ? (63 - idx) : (idx - 32);
    const int q0  = chunk * 32;        // 32-row chunk base

    const int tid = threadIdx.x;
    const int lane = tid & 63;
    const int w = tid >> 6;            // wave 0..7
    const int h = (w & 3) * 4 + g;     // query head = rep*KVH + g
    const int q0w = q0 + (w >> 2) * 16;  // this wave's 16-row q-tile
    // log2-domain: fold log2(e) into scale and slope
    const float slope2 = exp2f(-0.5f * (float)(h + 1)) * 1.4426950408889634f;
    const float isq2 = 0.088388347648318447f * 1.4426950408889634f; // log2e/sqrt(128)
    const int lrow = lane & 15;
    const int lko  = (lane >> 4) << 3;
    const int rowg = (lane >> 4) << 2;
    // K staging (512 threads): 2 x uint4 per thread
    const int skey = tid >> 4;                 // 0..31
    const int sd0  = (tid & 15) << 3;          // 0..120
    // V staging (512 threads): 2 key-groups x 8 keys per thread
    const int vdim = tid & 127;                // dim
    const int vkg  = tid >> 7;                 // 0..3

    uint4 kreg[2];                             // in-flight K tile (regs)
    unsigned short vv[2][8];                   // in-flight V tile (regs)

    auto ldK = [&](int kb) {
        const int j0 = kb << 6;
        #pragma unroll
        for (int pp = 0; pp < 2; ++pp) {
            const int key = skey + pp * 32;
            kreg[pp] = *reinterpret_cast<const uint4*>(
                &KVb[(size_t)(b * 2048 + j0 + key) * 1024 + g * 128 + sd0]);
        }
    };
    auto wrK = [&]() {
        #pragma unroll
        for (int pp = 0; pp < 2; ++pp) {
            const int key = skey + pp * 32;
            *reinterpret_cast<uint4*>(&Ksl[key][sd0 ^ ((key & 7) << 3)]) = kreg[pp];
        }
    };
    auto ldV = [&](int kb) {
        const int j0 = kb << 6;
        #pragma unroll
        for (int gi = 0; gi < 2; ++gi) {
            const int kgi = gi * 4 + vkg;
            const size_t base = (size_t)(b * 2048 + j0 + kgi * 8) * 1024 + 512 + g * 128 + vdim;
            #pragma unroll
            for (int j = 0; j < 8; ++j)
                vv[gi][j] = KVb[base + (size_t)j * 1024];
        }
    };
    auto wrV = [&]() {
        #pragma unroll
        for (int gi = 0; gi < 2; ++gi) {
            const int kgi = gi * 4 + vkg;
            *reinterpret_cast<uint4*>(&Vt[vdim][kgi * 8]) =
                *reinterpret_cast<const uint4*>(&vv[gi][0]);
        }
    };

    bf16x8 qf[4];
    {
        const size_t qoff = (size_t)(b * 2048 + q0w + lrow) * 2048 + h * 128 + lko;
        #pragma unroll
        for (int kk = 0; kk < 4; ++kk)
            qf[kk] = *reinterpret_cast<const bf16x8*>(&Qb[qoff + kk * 32]);
    }

    f32x4 oacc[8] = {};
    float mrow = NEG_BIG, lsum = 0.f;
    const int nkb = (q0 + 32 + 63) >> 6;       // block-uniform (covers both tiles)
    const int q = q0w + lrow;                  // this lane's q-row

    // loop-invariant per-element bias offsets: slope2 * (c*16 + rowg + r)
    float offs[4][4];
    #pragma unroll
    for (int c = 0; c < 4; ++c)
        #pragma unroll
        for (int r = 0; r < 4; ++r)
            offs[c][r] = slope2 * (float)(c * 16 + rowg + r);

    // prologue: stage tile 0
    ldK(0); ldV(0);
    wrK(); wrV();
    __syncthreads();

    for (int kb = 0; kb < nkb; ++kb) {
        const int j0 = kb << 6;
        const bool pre = (kb + 1 < nkb);
        if (pre) { ldK(kb + 1); ldV(kb + 1); }

        // S^T = K Q^T : lane owns q-row q, 16 keys in regs
        f32x4 sa[4] = {};
        #pragma unroll
        for (int c = 0; c < 4; ++c) {
            const int krow = c * 16 + lrow;
            #pragma unroll
            for (int kk = 0; kk < 4; ++kk) {
                bf16x8 kf = *reinterpret_cast<const bf16x8*>(
                    &Ksl[krow][(kk * 32 + lko) ^ ((krow & 7) << 3)]);
                sa[c] = __builtin_amdgcn_mfma_f32_16x16x32_bf16(kf, qf[kk], sa[c], 0, 0, 0);
            }
        }

        // in-lane softmax (log2 domain), one q-row per lane
        const float base_b = slope2 * (float)(j0 - q);
        const int qmj0 = q - j0;       // element c*16+rowg+r unmasked iff <= qmj0
        float pv[4][4];
        float mt = NEG_BIG;
        if (j0 + 63 <= q0w) {
            // fully unmasked for every lane of this wave
            #pragma unroll
            for (int c = 0; c < 4; ++c)
                #pragma unroll
                for (int r = 0; r < 4; ++r) {
                    const float vsc = fmaf(sa[c][r], isq2, base_b + offs[c][r]);
                    pv[c][r] = vsc;
                    mt = fmaxf(mt, vsc);
                }
        } else {
            #pragma unroll
            for (int c = 0; c < 4; ++c)
                #pragma unroll
                for (int r = 0; r < 4; ++r) {
                    const float vsc = (c * 16 + rowg + r <= qmj0)
                        ? fmaf(sa[c][r], isq2, base_b + offs[c][r]) : NEG_BIG;
                    pv[c][r] = vsc;
                    mt = fmaxf(mt, vsc);
                }
        }
        mt = fmaxf(mt, __shfl_xor(mt, 16));
        mt = fmaxf(mt, __shfl_xor(mt, 32));

        float s = 0.f;
        if (__all(mt - mrow <= 12.0f)) {
            // defer-max: keep old running max (P bounded by 2^12), alpha == 1
            #pragma unroll
            for (int c = 0; c < 4; ++c)
                #pragma unroll
                for (int r = 0; r < 4; ++r) {
                    const float pe = exp2f(pv[c][r] - mrow);
                    pv[c][r] = pe;
                    s += pe;
                }
            s += __shfl_xor(s, 16);
            s += __shfl_xor(s, 32);
            lsum += s;
        } else {
            const float mn = fmaxf(mrow, mt);
            const float alpha = exp2f(mrow - mn);
            mrow = mn;
            #pragma unroll
            for (int c = 0; c < 4; ++c)
                #pragma unroll
                for (int r = 0; r < 4; ++r) {
                    const float pe = exp2f(pv[c][r] - mn);
                    pv[c][r] = pe;
                    s += pe;
                }
            s += __shfl_xor(s, 16);
            s += __shfl_xor(s, 32);
            lsum = lsum * alpha + s;
            // redistribute alpha to PV accumulator rows (q = rowg + r)
            float ar[4];
            #pragma unroll
            for (int r = 0; r < 4; ++r) ar[r] = __shfl(alpha, rowg + r);
            #pragma unroll
            for (int f = 0; f < 8; ++f)
                #pragma unroll
                for (int r = 0; r < 4; ++r)
                    oacc[f][r] *= ar[r];
        }

        // P pack (cvt_pk) -> per-wave LDS, b64 writes
        #pragma unroll
        for (int c = 0; c < 4; ++c) {
            uint2 pw;
            pw.x = cvtpk(pv[c][0], pv[c][1]);
            pw.y = cvtpk(pv[c][2], pv[c][3]);
            *reinterpret_cast<uint2*>(&Psl[w][lrow][c * 16 + rowg]) = pw;
        }
        asm volatile("s_waitcnt lgkmcnt(0)" ::: "memory");

        #pragma unroll
        for (int kk2 = 0; kk2 < 2; ++kk2) {
            bf16x8 pf = *reinterpret_cast<const bf16x8*>(&Psl[w][lrow][kk2 * 32 + lko]);
            #pragma unroll
            for (int nb = 0; nb < 8; ++nb) {
                bf16x8 vf = *reinterpret_cast<const bf16x8*>(&Vt[nb * 16 + lrow][kk2 * 32 + lko]);
                oacc[nb] = __builtin_amdgcn_mfma_f32_16x16x32_bf16(pf, vf, oacc[nb], 0, 0, 0);
            }
        }

        __syncthreads();             // all waves done reading Ksl/Vt
        if (pre) { wrK(); wrV(); }
        __syncthreads();             // next tile visible
    }

    // epilogue
    float lr[4];
    #pragma unroll
    for (int r = 0; r < 4; ++r) lr[r] = __shfl(lsum, rowg + r);
    #pragma unroll
    for (int nb = 0; nb < 8; ++nb)
        #pragma unroll
        for (int r = 0; r < 4; ++r) {
            const int row = q0w + rowg + r;
            const int col = h * 128 + nb * 16 + lrow;
            const float vo = oacc[nb][r] / lr[r];
            AO[(size_t)(b * 2048 + row) * 2048 + col] = f2b(vo);
        }
}

extern "C" void kernel_launch(void* const* d_in, const int* in_sizes, int n_in,
                              void* d_out, int out_size, void* d_ws, size_t ws_size,
                              hipStream_t stream)
{
    const float* x   = (const float*)d_in[0];  // (2,2048,2048)
    const float* Wq  = (const float*)d_in[1];  // (2048,2048)
    const float* Wkv = (const float*)d_in[2];  // (2048,1024)
    const float* Wo  = (const float*)d_in[3];  // (2048,2048)
    const float* bo  = (const float*)d_in[4];  // (2048,)

    char* ws = (char*)d_ws;
    unsigned short* xb  = (unsigned short*)(ws + (size_t)0);          // 16MB (later AO)
    unsigned short* Wt  = (unsigned short*)(ws + ((size_t)16 << 20)); // 12MB (3072x2048)
    unsigned short* Qb  = (unsigned short*)(ws + ((size_t)28 << 20)); // 16MB
    unsigned short* KVb = (unsigned short*)(ws + ((size_t)44 << 20)); // 8MB
    // total 52MB

    // x -> bf16
    k_convert<<<8192, 256, 0, stream>>>(x, xb, (2 * 2048 * 2048) / 4);

    // Wt rows 0..2047 = Wq^T, rows 2048..3071 = Wkv^T
    k_transpose<<<dim3(32, 32), 256, 0, stream>>>(Wq, Wt, 2048, 2048);
    k_transpose<<<dim3(16, 32), 256, 0, stream>>>(Wkv, Wt + (size_t)2048 * 2048, 2048, 1024);

    // fused QKV = x @ [Wq | Wkv]  (4096 x 3072 x 2048), split outputs
    k_gemm<<<dim3(24, 32), 256, 0, stream>>>(xb, Wt, Qb, 2048, KVb, 1024, 2048,
                                             nullptr, 4096, 2048, 0);

    // attention -> AO (reuses x buffer)
    k_attn<<<512, 512, 0, stream>>>(Qb, KVb, xb);

    // out = AO @ Wo + bo   (4096 x 2048 x 2048), f32 out
    k_transpose<<<dim3(32, 32), 256, 0, stream>>>(Wo, Wt, 2048, 2048);
    k_gemm<<<dim3(16, 32), 256, 0, stream>>>(xb, Wt, d_out, 2048, nullptr, 2048, 2048,
                                             bo, 4096, 2048, 1);
}

// Round 13
// 246.673 us; speedup vs baseline: 2.1893x; 2.1893x over previous
//
#include <hip/hip_runtime.h>

typedef __attribute__((ext_vector_type(8))) __bf16 bf16x8;
typedef __attribute__((ext_vector_type(4))) float f32x4;

#define NEG_BIG (-1e30f)

__device__ __forceinline__ unsigned short f2b(float f) {
    unsigned int u = __float_as_uint(f);
    u += 0x7FFFu + ((u >> 16) & 1u);
    return (unsigned short)(u >> 16);
}
__device__ __forceinline__ float b2f(unsigned short h) {
    return __uint_as_float(((unsigned int)h) << 16);
}
__device__ __forceinline__ unsigned cvtpk(float lo, float hi) {
    unsigned r;
    asm("v_cvt_pk_bf16_f32 %0, %1, %2" : "=v"(r) : "v"(lo), "v"(hi));
    return r;
}

typedef const __attribute__((address_space(1))) unsigned int* gas_ptr;
typedef __attribute__((address_space(3))) unsigned int* las_ptr;
__device__ __forceinline__ void gload16(const void* g, void* l) {
    __builtin_amdgcn_global_load_lds((gas_ptr)g, (las_ptr)l, 16, 0, 0);
}

// ---------------- elementwise f32 -> bf16 (rn) ----------------
__global__ __launch_bounds__(256) void k_convert(
    const float* __restrict__ x, unsigned short* __restrict__ xb, int n4)
{
    int i = blockIdx.x * 256 + threadIdx.x;
    if (i >= n4) return;
    float4 v = reinterpret_cast<const float4*>(x)[i];
    ushort4 h;
    h.x = f2b(v.x); h.y = f2b(v.y); h.z = f2b(v.z); h.w = f2b(v.w);
    reinterpret_cast<ushort4*>(xb)[i] = h;
}

// ------------- W (K x N, f32) -> Wt (N x K) bf16 -------------
__global__ __launch_bounds__(256) void k_transpose(
    const float* __restrict__ W, unsigned short* __restrict__ Th, int K, int N)
{
    __shared__ float tile[64][65];
    const int n0 = blockIdx.x * 64, k0 = blockIdx.y * 64;
    const int c = threadIdx.x & 63, r0 = threadIdx.x >> 6;
    for (int rr = r0; rr < 64; rr += 4)
        tile[rr][c] = W[(size_t)(k0 + rr) * N + n0 + c];
    __syncthreads();
    for (int rr = r0; rr < 64; rr += 4)
        Th[(size_t)(n0 + rr) * K + k0 + c] = f2b(tile[c][rr]);
}

// ------------- plain bf16 GEMM: C = A * B^T(stored [N][K]) -------------
// BK=64, both-sides XOR swizzle: gload_lds keeps linear LDS dest, global
// SOURCE col unit pre-swizzled (u ^= row&7), ds_read applies the same XOR
// (rule #21). 64 barriers total (was 128), 32 MFMAs per barrier-pair.
// Split epilogue: cols < N1 -> CoutA, cols >= N1 -> CoutB.
__global__ __launch_bounds__(256) void k_gemm(
    const unsigned short* __restrict__ A, const unsigned short* __restrict__ B,
    void* __restrict__ CoutA, int NA, void* __restrict__ CoutB, int NB, int N1,
    const float* __restrict__ bias, int M, int K, int outF32)
{
    __shared__ __align__(16) unsigned short As[128][64];
    __shared__ __align__(16) unsigned short Bs[128][64];

    const int tid  = threadIdx.x;
    const int lane = tid & 63, wid = tid >> 6;
    const int wr = wid >> 1, wc = wid & 1;
    const int lrow = lane & 15, lko = (lane >> 4) << 3;
    const int bm = blockIdx.y, bn = blockIdx.x;

    // staging: row = s*32 + (tid>>3); source col unit pre-swizzled
    const int srow = tid >> 3;                       // 0..31
    const int scol = ((tid & 7) ^ (srow & 7)) << 3;  // pre-swizzled k-offset
    const int wbase = wid * 1024;                    // wave-uniform LDS base

    // fragment-read swizzle: row&7 == lrow&7 for every m/n
    const int sw = (lrow & 7) << 3;
    const int c0 = lko ^ sw;
    const int c1 = (32 + lko) ^ sw;

    f32x4 acc[4][4] = {};

    const size_t aoff = (size_t)(bm * 128 + srow) * K + scol;
    const size_t boff = (size_t)(bn * 128 + srow) * K + scol;
    const size_t slab = (size_t)32 * K;

    for (int k0 = 0; k0 < K; k0 += 64) {
        #pragma unroll
        for (int s = 0; s < 4; ++s) {
            gload16(&A[aoff + s * slab + k0], (char*)&As[0][0] + s * 4096 + wbase);
            gload16(&B[boff + s * slab + k0], (char*)&Bs[0][0] + s * 4096 + wbase);
        }
        __syncthreads();

        #pragma unroll
        for (int kk2 = 0; kk2 < 2; ++kk2) {
            const int cc = kk2 ? c1 : c0;
            bf16x8 af[4], bf[4];
            #pragma unroll
            for (int m = 0; m < 4; ++m)
                af[m] = *reinterpret_cast<const bf16x8*>(&As[wr * 64 + m * 16 + lrow][cc]);
            #pragma unroll
            for (int n = 0; n < 4; ++n)
                bf[n] = *reinterpret_cast<const bf16x8*>(&Bs[wc * 64 + n * 16 + lrow][cc]);
            #pragma unroll
            for (int m = 0; m < 4; ++m)
                #pragma unroll
                for (int n = 0; n < 4; ++n)
                    acc[m][n] = __builtin_amdgcn_mfma_f32_16x16x32_bf16(af[m], bf[n], acc[m][n], 0, 0, 0);
        }
        __syncthreads();
    }

    const int rbase = bm * 128 + wr * 64 + ((lane >> 4) << 2);
    const int cbase = bn * 128 + wc * 64 + lrow;
    #pragma unroll
    for (int m = 0; m < 4; ++m)
        #pragma unroll
        for (int n = 0; n < 4; ++n) {
            const int col = cbase + n * 16;
            const float bv = bias ? bias[col] : 0.0f;
            const bool inA = (col < N1);
            const int ccol = inA ? col : (col - N1);
            const int cstr = inA ? NA : NB;
            void* base = inA ? CoutA : CoutB;
            #pragma unroll
            for (int r = 0; r < 4; ++r) {
                const size_t idx = (size_t)(rbase + m * 16 + r) * cstr + ccol;
                const float v = acc[m][n][r] + bv;
                if (outF32) ((float*)base)[idx] = v;
                else        ((unsigned short*)base)[idx] = f2b(v);
            }
        }
}

// ------------- fused causal GQA attention with ALiBi -------------
// (verified round-11 version, byte-identical) block = (b, g, 32-row q-chunk),
// 8 waves: waves 0-3 = q-tile q0, waves 4-7 = q-tile q0+16 (same kv head g).
// Shared K/V staging; complementary chunk mapping for CU load balance.
__global__ __launch_bounds__(512, 4) void k_attn(
    const unsigned short* __restrict__ Qb,   // (B*T) x 2048 bf16
    const unsigned short* __restrict__ KVb,  // (B*T) x 1024 bf16 (k | v)
    unsigned short* __restrict__ AO)         // (B*T) x 2048 bf16
{
    __shared__ __align__(16) unsigned short Ksl[64][128]; // [key][dim ^ ((key&7)<<3)]
    __shared__ __align__(16) unsigned short Vt[128][72];  // [dim][key], padded
    __shared__ __align__(16) unsigned short Psl[8][16][72];

    const int blk = blockIdx.x;
    const int idx = blk >> 3;          // 0..63
    const int sub = blk & 7;
    const int b   = sub >> 2;
    const int g   = sub & 3;
    const int chunk = (idx < 32) ? (63 - idx) : (idx - 32);
    const int q0  = chunk * 32;        // 32-row chunk base

    const int tid = threadIdx.x;
    const int lane = tid & 63;
    const int w = tid >> 6;            // wave 0..7
    const int h = (w & 3) * 4 + g;     // query head = rep*KVH + g
    const int q0w = q0 + (w >> 2) * 16;  // this wave's 16-row q-tile
    const float slope = exp2f(-0.5f * (float)(h + 1));
    const float isq = 0.088388347648318447f; // 1/sqrt(128)
    const int lrow = lane & 15;
    const int lko  = (lane >> 4) << 3;
    const int rowg = (lane >> 4) << 2;
    // K staging (512 threads): 2 x uint4 per thread
    const int skey = tid >> 4;                 // 0..31
    const int sd0  = (tid & 15) << 3;          // 0..120
    // V staging (512 threads): 2 key-groups x 8 keys per thread
    const int vdim = tid & 127;                // dim
    const int vkg  = tid >> 7;                 // 0..3

    uint4 kreg[2];                             // in-flight K tile (regs)
    unsigned short vv[2][8];                   // in-flight V tile (regs)

    auto ldK = [&](int kb) {
        const int j0 = kb << 6;
        #pragma unroll
        for (int pp = 0; pp < 2; ++pp) {
            const int key = skey + pp * 32;
            kreg[pp] = *reinterpret_cast<const uint4*>(
                &KVb[(size_t)(b * 2048 + j0 + key) * 1024 + g * 128 + sd0]);
        }
    };
    auto wrK = [&]() {
        #pragma unroll
        for (int pp = 0; pp < 2; ++pp) {
            const int key = skey + pp * 32;
            *reinterpret_cast<uint4*>(&Ksl[key][sd0 ^ ((key & 7) << 3)]) = kreg[pp];
        }
    };
    auto ldV = [&](int kb) {
        const int j0 = kb << 6;
        #pragma unroll
        for (int gi = 0; gi < 2; ++gi) {
            const int kgi = gi * 4 + vkg;
            const size_t base = (size_t)(b * 2048 + j0 + kgi * 8) * 1024 + 512 + g * 128 + vdim;
            #pragma unroll
            for (int j = 0; j < 8; ++j)
                vv[gi][j] = KVb[base + (size_t)j * 1024];
        }
    };
    auto wrV = [&]() {
        #pragma unroll
        for (int gi = 0; gi < 2; ++gi) {
            const int kgi = gi * 4 + vkg;
            *reinterpret_cast<uint4*>(&Vt[vdim][kgi * 8]) =
                *reinterpret_cast<const uint4*>(&vv[gi][0]);
        }
    };

    bf16x8 qf[4];
    {
        const size_t qoff = (size_t)(b * 2048 + q0w + lrow) * 2048 + h * 128 + lko;
        #pragma unroll
        for (int kk = 0; kk < 4; ++kk)
            qf[kk] = *reinterpret_cast<const bf16x8*>(&Qb[qoff + kk * 32]);
    }

    f32x4 oacc[8] = {};
    float mrow = NEG_BIG, lsum = 0.f;
    const int nkb = (q0 + 32 + 63) >> 6;       // block-uniform (covers both tiles)
    const int q = q0w + lrow;                  // this lane's q-row

    // prologue: stage tile 0
    ldK(0); ldV(0);
    wrK(); wrV();
    __syncthreads();

    for (int kb = 0; kb < nkb; ++kb) {
        const int j0 = kb << 6;
        const bool pre = (kb + 1 < nkb);
        if (pre) { ldK(kb + 1); ldV(kb + 1); }

        // S^T = K Q^T : lane owns q-row q, 16 keys in regs
        f32x4 sa[4] = {};
        #pragma unroll
        for (int c = 0; c < 4; ++c) {
            const int krow = c * 16 + lrow;
            #pragma unroll
            for (int kk = 0; kk < 4; ++kk) {
                bf16x8 kf = *reinterpret_cast<const bf16x8*>(
                    &Ksl[krow][(kk * 32 + lko) ^ ((krow & 7) << 3)]);
                sa[c] = __builtin_amdgcn_mfma_f32_16x16x32_bf16(kf, qf[kk], sa[c], 0, 0, 0);
            }
        }

        // in-lane softmax over 16 values (one q-row per lane)
        float pv[4][4];
        float mt = NEG_BIG;
        #pragma unroll
        for (int c = 0; c < 4; ++c)
            #pragma unroll
            for (int r = 0; r < 4; ++r) {
                const int j = j0 + c * 16 + rowg + r;
                const float vsc = (j <= q) ? (sa[c][r] * isq + slope * (float)(j - q)) : NEG_BIG;
                pv[c][r] = vsc;
                mt = fmaxf(mt, vsc);
            }
        mt = fmaxf(mt, __shfl_xor(mt, 16));
        mt = fmaxf(mt, __shfl_xor(mt, 32));
        const float mn = fmaxf(mrow, mt);
        const float alpha = __expf(mrow - mn);
        mrow = mn;
        float s = 0.f;
        #pragma unroll
        for (int c = 0; c < 4; ++c)
            #pragma unroll
            for (int r = 0; r < 4; ++r) {
                const float pe = __expf(pv[c][r] - mn);
                pv[c][r] = pe;
                s += pe;
            }
        s += __shfl_xor(s, 16);
        s += __shfl_xor(s, 32);
        lsum = lsum * alpha + s;

        // redistribute alpha to PV accumulator rows (q = rowg + r)
        float ar[4];
        #pragma unroll
        for (int r = 0; r < 4; ++r) ar[r] = __shfl(alpha, rowg + r);
        #pragma unroll
        for (int f = 0; f < 8; ++f)
            #pragma unroll
            for (int r = 0; r < 4; ++r)
                oacc[f][r] *= ar[r];

        // P pack (cvt_pk) -> per-wave LDS, b64 writes
        #pragma unroll
        for (int c = 0; c < 4; ++c) {
            uint2 pw;
            pw.x = cvtpk(pv[c][0], pv[c][1]);
            pw.y = cvtpk(pv[c][2], pv[c][3]);
            *reinterpret_cast<uint2*>(&Psl[w][lrow][c * 16 + rowg]) = pw;
        }
        asm volatile("s_waitcnt lgkmcnt(0)" ::: "memory");

        #pragma unroll
        for (int kk2 = 0; kk2 < 2; ++kk2) {
            bf16x8 pf = *reinterpret_cast<const bf16x8*>(&Psl[w][lrow][kk2 * 32 + lko]);
            #pragma unroll
            for (int nb = 0; nb < 8; ++nb) {
                bf16x8 vf = *reinterpret_cast<const bf16x8*>(&Vt[nb * 16 + lrow][kk2 * 32 + lko]);
                oacc[nb] = __builtin_amdgcn_mfma_f32_16x16x32_bf16(pf, vf, oacc[nb], 0, 0, 0);
            }
        }

        __syncthreads();             // all waves done reading Ksl/Vt
        if (pre) { wrK(); wrV(); }
        __syncthreads();             // next tile visible
    }

    // epilogue
    float lr[4];
    #pragma unroll
    for (int r = 0; r < 4; ++r) lr[r] = __shfl(lsum, rowg + r);
    #pragma unroll
    for (int nb = 0; nb < 8; ++nb)
        #pragma unroll
        for (int r = 0; r < 4; ++r) {
            const int row = q0w + rowg + r;
            const int col = h * 128 + nb * 16 + lrow;
            const float vo = oacc[nb][r] / lr[r];
            AO[(size_t)(b * 2048 + row) * 2048 + col] = f2b(vo);
        }
}

extern "C" void kernel_launch(void* const* d_in, const int* in_sizes, int n_in,
                              void* d_out, int out_size, void* d_ws, size_t ws_size,
                              hipStream_t stream)
{
    const float* x   = (const float*)d_in[0];  // (2,2048,2048)
    const float* Wq  = (const float*)d_in[1];  // (2048,2048)
    const float* Wkv = (const float*)d_in[2];  // (2048,1024)
    const float* Wo  = (const float*)d_in[3];  // (2048,2048)
    const float* bo  = (const float*)d_in[4];  // (2048,)

    char* ws = (char*)d_ws;
    unsigned short* xb  = (unsigned short*)(ws + (size_t)0);          // 16MB (later AO)
    unsigned short* Wt  = (unsigned short*)(ws + ((size_t)16 << 20)); // 12MB (3072x2048)
    unsigned short* Qb  = (unsigned short*)(ws + ((size_t)28 << 20)); // 16MB
    unsigned short* KVb = (unsigned short*)(ws + ((size_t)44 << 20)); // 8MB
    // total 52MB

    // x -> bf16
    k_convert<<<8192, 256, 0, stream>>>(x, xb, (2 * 2048 * 2048) / 4);

    // Wt rows 0..2047 = Wq^T, rows 2048..3071 = Wkv^T
    k_transpose<<<dim3(32, 32), 256, 0, stream>>>(Wq, Wt, 2048, 2048);
    k_transpose<<<dim3(16, 32), 256, 0, stream>>>(Wkv, Wt + (size_t)2048 * 2048, 2048, 1024);

    // fused QKV = x @ [Wq | Wkv]  (4096 x 3072 x 2048), split outputs
    k_gemm<<<dim3(24, 32), 256, 0, stream>>>(xb, Wt, Qb, 2048, KVb, 1024, 2048,
                                             nullptr, 4096, 2048, 0);

    // attention -> AO (reuses x buffer)
    k_attn<<<512, 512, 0, stream>>>(Qb, KVb, xb);

    // out = AO @ Wo + bo   (4096 x 2048 x 2048), f32 out
    k_transpose<<<dim3(32, 32), 256, 0, stream>>>(Wo, Wt, 2048, 2048);
    k_gemm<<<dim3(16, 32), 256, 0, stream>>>(xb, Wt, d_out, 2048, nullptr, 2048, 2048,
                                             bo, 4096, 2048, 1);
}